// Round 4
// baseline (114.667 us; speedup 1.0000x reference)
//
#include <hip/hip_runtime.h>
#include <hip/hip_bf16.h>
#include <stdint.h>

typedef __attribute__((ext_vector_type(8))) short short8;
typedef __attribute__((ext_vector_type(4))) float f32x4;
typedef unsigned short u16;

#define AS1 __attribute__((address_space(1)))
#define AS3 __attribute__((address_space(3)))

__device__ __forceinline__ u16 f2b(float f) {
  union { float f; uint32_t u; } c; c.f = f;
  uint32_t u = c.u;
  return (u16)((u + 0x7fffu + ((u >> 16) & 1u)) >> 16);  // RNE
}
__device__ __forceinline__ float b2f(u16 b) {
  union { uint32_t u; float f; } c; c.u = ((uint32_t)b) << 16;
  return c.f;
}

// ---------------- conversion kernels (verified round 1) ----------------
__global__ void cvt_bf16_kernel(const float* __restrict__ src,
                                u16* __restrict__ dst, int n4) {
  int i = blockIdx.x * blockDim.x + threadIdx.x;
  if (i >= n4) return;
  const float4 v = reinterpret_cast<const float4*>(src)[i];
  ushort4 o;
  o.x = f2b(v.x); o.y = f2b(v.y); o.z = f2b(v.z); o.w = f2b(v.w);
  reinterpret_cast<ushort4*>(dst)[i] = o;
}

__global__ void cvt_transpose_kernel(const float* __restrict__ w0,
                                     const float* __restrict__ w1,
                                     const float* __restrict__ w2,
                                     u16* __restrict__ d0,
                                     u16* __restrict__ d1,
                                     u16* __restrict__ d2,
                                     int K, int N) {
  const float* src = (blockIdx.y == 0) ? w0 : (blockIdx.y == 1 ? w1 : w2);
  u16* dst = (blockIdx.y == 0) ? d0 : (blockIdx.y == 1 ? d1 : d2);
  int idx = blockIdx.x * blockDim.x + threadIdx.x;
  if (idx >= K * N) return;
  int k = idx / N, n = idx - k * N;
  dst[(size_t)n * K + k] = f2b(src[idx]);
}

// ---------------- 128x128 triple-buffered 2-tile-ahead GEMM ----------------
// C[16384,N] = A[.,1024] @ Wt[N][1024]^T.  BM=BN=128, BK=32, NT=32 K-tiles.
// 256 thr = 4 waves (2M x 2N); per-wave 64x64 output (acc 4x4 16x16 frags).
// LDS: 3 bufs x (A 8KB + B 8KB) = 48 KB -> 3 blocks/CU (gates) / 2 (cand),
// each block an independent barrier domain => cross-block overlap hides the
// stage/drain/barrier serialization seen in round 3 (MfmaUtil 28%).
// Pipeline (proven round 3): during tile kt, issue ALL 4 stage insts for
// tile kt+2 into buf[(kt+2)%3]; end-of-tile VMW(4) leaves only those 4
// outstanding => tile kt+1 fully landed before barrier releases readers.
// buf[(kt+2)%3]==buf[(kt-1)%3] was last read before the PREVIOUS barrier =>
// no WAR hazard.  One barrier/tile.
// Swizzle (verified conflict-free round 3): 64-B rows = 4 x 16B slots;
// slot ^= (row>>1)&3 on the global source (linear global_load_lds dest)
// AND on ds_read addresses.

#define BAR() do { __builtin_amdgcn_s_barrier(); __builtin_amdgcn_sched_barrier(0); } while (0)
#define VMW(n) asm volatile("s_waitcnt vmcnt(" #n ")" ::: "memory")

template <int NBN, int EPI>
__global__ __launch_bounds__(256, 3) void gemm_kernel(
    const u16* __restrict__ a1,       // A cols 0..511    [16384,512] bf16
    const u16* __restrict__ a2,       // A cols 512..1023 [16384,512] bf16
    const u16* __restrict__ wt,       // weights^T [N][1024] bf16
    const float* __restrict__ hprev,  // h_prev f32 [16384,512]
    const u16* __restrict__ zb_in,    // z bf16 (EPI=1)
    u16* __restrict__ o_z,            // EPI=0
    u16* __restrict__ o_rh,           // EPI=0
    float* __restrict__ o_f) {        // EPI=1
  constexpr int NT = 32;
  constexpr int ATILE_E = 4096;       // A tile u16 (128x32)
  constexpr int BUF_E = 8192;         // A + B tile u16

  __shared__ u16 lds[3 * BUF_E];

  const int tid = threadIdx.x;
  const int lane = tid & 63;
  const int wid = tid >> 6;           // 0..3
  const int wm = wid >> 1;            // 0..1
  const int wn = wid & 1;             // 0..1

  // XCD-chunked bijective swizzle; grid = 128*NBN (divisible by 8)
  const int cpx = (128 * NBN) >> 3;
  const int wg = ((int)blockIdx.x & 7) * cpx + ((int)blockIdx.x >> 3);
  const int bn = wg & (NBN - 1);
  const int bm = wg / NBN;

  // ---- staging addresses.  Each stage inst: 256 lanes x 16B = 4096 B =
  // 64 rows x 64 B.  LDS row = iblk*64 + wid*16 + (lane>>2), slot = lane&3.
  // Source slot = slot ^ ((row>>1)&3) = (lane&3) ^ ((lane>>3)&3).
  const int srow = wid * 16 + (lane >> 2);
  const int scol = ((lane & 3) ^ ((lane >> 3) & 3)) << 4;   // bytes
  const size_t aoff = (size_t)srow * 1024 + scol;           // A row = 1024 B
  const size_t boff = (size_t)srow * 2048 + scol;           // B row = 2048 B
  const size_t abase_g = (size_t)bm * 131072;               // bm*128 rows * 1024 B
  const size_t bbase_g = (size_t)bn * 262144;               // bn*128 rows * 2048 B

  auto STAGE = [&](int ktn, u16* buf) {
    const char* asn = (ktn < 16) ? ((const char*)a1 + abase_g + (size_t)ktn * 64)
                                 : ((const char*)a2 + abase_g + (size_t)(ktn - 16) * 64);
    const char* bsn = (const char*)wt + bbase_g + (size_t)ktn * 64;
    __builtin_amdgcn_global_load_lds((const AS1 void*)(asn + aoff),
                                     (AS3 void*)(buf + wid * 512), 16, 0, 0);
    __builtin_amdgcn_global_load_lds((const AS1 void*)(asn + 65536 + aoff),
                                     (AS3 void*)(buf + 2048 + wid * 512), 16, 0, 0);
    __builtin_amdgcn_global_load_lds((const AS1 void*)(bsn + boff),
                                     (AS3 void*)(buf + ATILE_E + wid * 512), 16, 0, 0);
    __builtin_amdgcn_global_load_lds((const AS1 void*)(bsn + 131072 + boff),
                                     (AS3 void*)(buf + ATILE_E + 2048 + wid * 512), 16, 0, 0);
  };

  // ---- frag-read addresses (swizzled): lane = kg*16 + rsel reads row
  // base+rsel, k-slot kg; (row>>1)&3 == (rsel>>1)&3 since bases are x16.
  const int rsel = lane & 15;
  const int kg = lane >> 4;
  const int rcol = (kg ^ ((rsel >> 1) & 3)) << 4;
  const int abyte = (wm * 64 + rsel) * 64 + rcol;            // + mf*1024
  const int bbyte = 8192 + (wn * 64 + rsel) * 64 + rcol;     // + nf*1024

  f32x4 acc[4][4] = {};

  // prologue: tiles 0 and 1 in flight; wait tile 0 landed
  STAGE(0, lds);
  STAGE(1, lds + BUF_E);
  VMW(4);
  BAR();

  int cb = 0;
  for (int kt = 0; kt < NT; ++kt) {
    u16* cur = lds + cb * BUF_E;
    const bool st = (kt + 2) < NT;
    if (st) {
      int nb = cb + 2; if (nb >= 3) nb -= 3;
      STAGE(kt + 2, lds + nb * BUF_E);
    }
    short8 bv[4];
#pragma unroll
    for (int nf = 0; nf < 4; ++nf)
      bv[nf] = *(const short8*)((const char*)cur + bbyte + nf * 1024);
    __builtin_amdgcn_s_setprio(1);
#pragma unroll
    for (int mf = 0; mf < 4; ++mf) {
      const short8 av = *(const short8*)((const char*)cur + abyte + mf * 1024);
#pragma unroll
      for (int nf = 0; nf < 4; ++nf)
        acc[mf][nf] = __builtin_amdgcn_mfma_f32_16x16x32_bf16(av, bv[nf], acc[mf][nf], 0, 0, 0);
    }
    __builtin_amdgcn_s_setprio(0);
    if (st) VMW(4); else VMW(0);
    BAR();
    ++cb; if (cb == 3) cb = 0;
  }

  // ---- epilogue.  C/D: col = rsel (B-row), row = kg*4 + q (A-row).
  const int row0 = bm * 128 + wm * 64 + kg * 4;
  const int col0 = bn * 128 + wn * 64 + rsel;
  if constexpr (EPI == 0) {
    if (bn < 4) {  // z half (global cols 0..511), block-uniform branch
#pragma unroll
      for (int mf = 0; mf < 4; ++mf)
#pragma unroll
        for (int nf = 0; nf < 4; ++nf)
#pragma unroll
          for (int q = 0; q < 4; ++q) {
            const int row = row0 + mf * 16 + q;
            const int col = col0 + nf * 16;
            const float zf = 1.f / (1.f + __expf(-acc[mf][nf][q]));
            o_z[(size_t)row * 512 + col] = f2b(zf);
          }
    } else {       // r half (global cols 512..1023)
#pragma unroll
      for (int mf = 0; mf < 4; ++mf)
#pragma unroll
        for (int nf = 0; nf < 4; ++nf)
#pragma unroll
          for (int q = 0; q < 4; ++q) {
            const int row = row0 + mf * 16 + q;
            const int col = col0 + nf * 16 - 512;
            const size_t idx = (size_t)row * 512 + col;
            const float rf = 1.f / (1.f + __expf(-acc[mf][nf][q]));
            o_rh[idx] = f2b(rf * hprev[idx]);
          }
    }
  } else {
#pragma unroll
    for (int mf = 0; mf < 4; ++mf)
#pragma unroll
      for (int nf = 0; nf < 4; ++nf)
#pragma unroll
        for (int q = 0; q < 4; ++q) {
          const int row = row0 + mf * 16 + q;
          const int col = col0 + nf * 16;
          const size_t idx = (size_t)row * 512 + col;
          const float s = acc[mf][nf][q];
          const float hh = 2.f / (1.f + __expf(-2.f * s)) - 1.f;  // tanh
          const float z = b2f(zb_in[idx]);
          o_f[idx] = z * hprev[idx] + (1.f - z) * hh;
        }
  }
}

// ---------------- launch ----------------
extern "C" void kernel_launch(void* const* d_in, const int* in_sizes, int n_in,
                              void* d_out, int out_size, void* d_ws, size_t ws_size,
                              hipStream_t stream) {
  const float* inputs = (const float*)d_in[0];
  const float* h_prev = (const float*)d_in[1];
  const float* Wz = (const float*)d_in[2];
  const float* Wr = (const float*)d_in[3];
  const float* Wh = (const float*)d_in[4];
  float* out = (float*)d_out;

  const int B = 16384, D = 512, U = 512, K = 1024;

  u16* xb = (u16*)d_ws;                 // [B,D] bf16
  u16* hb = xb + (size_t)B * D;         // [B,U] bf16
  u16* wzt = hb + (size_t)B * U;        // [1024,1024]: rows 0-511 Wz^T, 512-1023 Wr^T
  u16* wrt = wzt + (size_t)K * U;
  u16* wht = wrt + (size_t)K * U;       // [512,1024] Wh^T
  u16* zb = wht + (size_t)K * U;        // [B,U] bf16
  u16* rhb = zb + (size_t)B * U;        // [B,U] bf16

  const int n4 = (B * D) / 4;
  cvt_bf16_kernel<<<(n4 + 255) / 256, 256, 0, stream>>>(inputs, xb, n4);
  cvt_bf16_kernel<<<(n4 + 255) / 256, 256, 0, stream>>>(h_prev, hb, n4);
  dim3 tg((K * U + 255) / 256, 3);
  cvt_transpose_kernel<<<tg, 256, 0, stream>>>(Wz, Wr, Wh, wzt, wrt, wht, K, U);

  // gates: N=1024 (z|r), NBN=8 -> grid 128*8 = 1024 blocks (3/CU resident)
  gemm_kernel<8, 0><<<dim3(1024), 256, 0, stream>>>(xb, hb, wzt, h_prev, nullptr, zb, rhb, nullptr);
  // candidate: N=512, NBN=4 -> grid 128*4 = 512 blocks (2/CU)
  gemm_kernel<4, 1><<<dim3(512), 256, 0, stream>>>(xb, rhb, wht, h_prev, zb, nullptr, nullptr, out);
}

// Round 5
// 99.488 us; speedup vs baseline: 1.1526x; 1.1526x over previous
//
#include <hip/hip_runtime.h>
#include <hip/hip_bf16.h>
#include <stdint.h>

typedef __attribute__((ext_vector_type(8))) short short8;
typedef __attribute__((ext_vector_type(4))) float f32x4;
typedef unsigned short u16;

#define AS1 __attribute__((address_space(1)))
#define AS3 __attribute__((address_space(3)))

__device__ __forceinline__ u16 f2b(float f) {
  union { float f; uint32_t u; } c; c.f = f;
  uint32_t u = c.u;
  return (u16)((u + 0x7fffu + ((u >> 16) & 1u)) >> 16);  // RNE
}
__device__ __forceinline__ float b2f(u16 b) {
  union { uint32_t u; float f; } c; c.u = ((uint32_t)b) << 16;
  return c.f;
}

// ---------------- conversion kernels (verified round 1) ----------------
__global__ void cvt_bf16_kernel(const float* __restrict__ src,
                                u16* __restrict__ dst, int n4) {
  int i = blockIdx.x * blockDim.x + threadIdx.x;
  if (i >= n4) return;
  const float4 v = reinterpret_cast<const float4*>(src)[i];
  ushort4 o;
  o.x = f2b(v.x); o.y = f2b(v.y); o.z = f2b(v.z); o.w = f2b(v.w);
  reinterpret_cast<ushort4*>(dst)[i] = o;
}

__global__ void cvt_transpose_kernel(const float* __restrict__ w0,
                                     const float* __restrict__ w1,
                                     const float* __restrict__ w2,
                                     u16* __restrict__ d0,
                                     u16* __restrict__ d1,
                                     u16* __restrict__ d2,
                                     int K, int N) {
  const float* src = (blockIdx.y == 0) ? w0 : (blockIdx.y == 1 ? w1 : w2);
  u16* dst = (blockIdx.y == 0) ? d0 : (blockIdx.y == 1 ? d1 : d2);
  int idx = blockIdx.x * blockDim.x + threadIdx.x;
  if (idx >= K * N) return;
  int k = idx / N, n = idx - k * N;
  dst[(size_t)n * K + k] = f2b(src[idx]);
}

// ---------------- m201-style 8-phase 256-wide pipelined GEMM ----------------
// C[16384,N] = A[.,1024] @ Wt[N][1024]^T.  BM=256, BK=64, NT=16 K-tiles,
// 8 iters x 2 tiles.  512 thr = 8 waves.  GATES: BN=256, waves 2Mx4N
// (per-wave 128x64).  CAND: BN=128, waves 4Mx2N (per-wave 64x64).
// LDS: 2 dbufs, each = one K-tile: A halves (kind 0,1) + B halves (kind 2[,3]).
// Each iter: phases 0-3 compute tile 2j (dbuf0), 4-7 tile 2j+1 (dbuf1).
// Stage stream (1 half-tile = 2 global_load_lds per phase):
//   ph0:A0(2j+1) ph1:A1(2j+1) ph2:B0(2j+2) ph3:B1|A0(2j+2) ph4:A0|A1(2j+2)
//   ph5:A1(2j+2)|- ph6:B0(2j+3) ph7:B1(2j+3)|-
// WAR: each region's write phase > its last-read phase (A read ph0&2, B ph0&1;
// mirrored +4 for dbuf1), with a full barrier between.  Landing deadlines:
// tile 2j+1 landed by ph3's VMW (allows ph2,ph3 stages = 4 loads out);
// tile 2j+2 by ph7's VMW (gates 4, cand 2 loads out).  Last iter drains 0.
// Swizzle (0 conflicts, verified round 3): 128B rows = 8 x 16B slots;
// slot ^= row&7 via pre-swizzled global source + swizzled ds_read col.

#define BARO() do { __builtin_amdgcn_s_barrier(); __builtin_amdgcn_sched_barrier(0); } while (0)
#define LGKM0() do { asm volatile("s_waitcnt lgkmcnt(0)" ::: "memory"); __builtin_amdgcn_sched_barrier(0); } while (0)
#define VMW(n) do { asm volatile("s_waitcnt vmcnt(" #n ")" ::: "memory"); __builtin_amdgcn_sched_barrier(0); } while (0)
#define PRIO_MM(MB, NB) do { __builtin_amdgcn_s_setprio(1); mm(MB, NB); __builtin_amdgcn_s_setprio(0); } while (0)

template <int GATES>
__global__ __launch_bounds__(512, 1) void gemm8_kernel(
    const u16* __restrict__ a1,       // A cols 0..511    [16384,512] bf16
    const u16* __restrict__ a2,       // A cols 512..1023 [16384,512] bf16
    const u16* __restrict__ wt,       // weights^T [N][1024] bf16
    const float* __restrict__ hprev,  // h_prev f32
    const u16* __restrict__ zb_in,    // z bf16 (cand)
    u16* __restrict__ o_z,            // gates
    u16* __restrict__ o_rh,           // gates
    float* __restrict__ o_f) {        // cand
  constexpr int NT = 16;
  constexpr int NITER = 8;
  constexpr int BN = GATES ? 256 : 128;
  constexpr int MQ = GATES ? 4 : 2;         // mf per quadrant
  constexpr int AHALF = GATES ? 16384 : 8192;  // per-wave A-half byte span
  constexpr int DBUF_E = GATES ? 32768 : 24576;  // u16 per dbuf
  constexpr int DB1 = DBUF_E * 2;           // byte offset of dbuf1

  __shared__ u16 lds[2 * DBUF_E];
  const char* ldsb = (const char*)lds;

  const int tid = threadIdx.x;
  const int lane = tid & 63;
  const int wid = tid >> 6;
  const int wm = GATES ? (wid >> 2) : (wid >> 1);
  const int wn = GATES ? (wid & 3) : (wid & 1);

  // XCD-chunked bijective swizzle (grid 256 = 8*32); nbn = 4 both kernels
  const int wg = ((int)blockIdx.x & 7) * 32 + ((int)blockIdx.x >> 3);
  const int bn = wg & 3;
  const int bm = wg >> 2;

  // ---- staging addressing: one inst = 512 lanes x 16B = 64 rows x 128 B.
  const int srow8 = tid >> 3;                                // row in inst
  const int swzb = ((tid & 7) ^ (srow8 & 7)) << 4;           // swizzled slot
  auto STAGE = [&](int t, int kind) {
    if (t >= NT) return;
    u16* dst = lds + (t & 1) * DBUF_E + kind * 8192 + wid * 512;
    if (kind < 2) {  // A half
      const char* src = ((t < 8) ? ((const char*)a1 + (size_t)t * 128)
                                 : ((const char*)a2 + (size_t)(t - 8) * 128)) +
                        (size_t)(bm * 256 + kind * 128 + srow8) * 1024 + swzb;
      __builtin_amdgcn_global_load_lds((const AS1 void*)src, (AS3 void*)dst, 16, 0, 0);
      __builtin_amdgcn_global_load_lds((const AS1 void*)(src + 65536), (AS3 void*)(dst + 4096), 16, 0, 0);
    } else {         // B half
      const char* src = (const char*)wt +
                        (size_t)(bn * BN + (kind - 2) * 128 + srow8) * 2048 +
                        (size_t)t * 128 + swzb;
      __builtin_amdgcn_global_load_lds((const AS1 void*)src, (AS3 void*)dst, 16, 0, 0);
      __builtin_amdgcn_global_load_lds((const AS1 void*)(src + 131072), (AS3 void*)(dst + 4096), 16, 0, 0);
    }
  };

  // ---- frag-read addressing (swizzled)
  const int rsel = lane & 15;
  const int kg = lane >> 4;
  const int sl0 = (kg ^ (rsel & 7)) << 4;          // ksub 0
  const int sl1 = ((4 + kg) ^ (rsel & 7)) << 4;    // ksub 1
  const int aoff0 = wm * AHALF + rsel * 128;
  const int boff0 = 32768 + wn * 8192 + rsel * 128;

  f32x4 acc[2 * MQ][4] = {};
  short8 a[MQ][2], b[4][2];

  auto ldA = [&](int DB, int mfb) {
#pragma unroll
    for (int mi = 0; mi < MQ; ++mi) {
      a[mi][0] = *(const short8*)(ldsb + DB + aoff0 + (mfb + mi) * 2048 + sl0);
      a[mi][1] = *(const short8*)(ldsb + DB + aoff0 + (mfb + mi) * 2048 + sl1);
    }
  };
  auto ldB = [&](int DB, int nfb) {
#pragma unroll
    for (int ni = 0; ni < 2; ++ni) {
      b[nfb + ni][0] = *(const short8*)(ldsb + DB + boff0 + (nfb + ni) * 2048 + sl0);
      b[nfb + ni][1] = *(const short8*)(ldsb + DB + boff0 + (nfb + ni) * 2048 + sl1);
    }
  };
  auto mm = [&](int mb, int nb) {
#pragma unroll
    for (int mi = 0; mi < MQ; ++mi)
#pragma unroll
      for (int ni = 0; ni < 2; ++ni) {
        acc[mb + mi][nb + ni] = __builtin_amdgcn_mfma_f32_16x16x32_bf16(a[mi][0], b[nb + ni][0], acc[mb + mi][nb + ni], 0, 0, 0);
        acc[mb + mi][nb + ni] = __builtin_amdgcn_mfma_f32_16x16x32_bf16(a[mi][1], b[nb + ni][1], acc[mb + mi][nb + ni], 0, 0, 0);
      }
  };

  // ---- prologue: stream B0,B1?,A0,A1 of tile0 + B half(s) of tile1
  if constexpr (GATES) {
    STAGE(0, 2); STAGE(0, 3); STAGE(0, 0); STAGE(0, 1); STAGE(1, 2); STAGE(1, 3);
    VMW(4);   // tile 0 (8 loads) landed; tile1 B halves in flight
  } else {
    STAGE(0, 2); STAGE(0, 0); STAGE(0, 1); STAGE(1, 2);
    VMW(2);   // tile 0 (6 loads) landed
  }
  BARO();

  for (int j = 0; j < NITER; ++j) {
    const int t1 = 2 * j + 1, t2 = 2 * j + 2, t3 = 2 * j + 3;
    // ---- ph0: tile 2j / dbuf0
    ldA(0, 0); ldB(0, 0); STAGE(t1, 0);
    BARO(); LGKM0(); PRIO_MM(0, 0); BARO();
    // ---- ph1
    ldB(0, 2); STAGE(t1, 1);
    BARO(); LGKM0(); PRIO_MM(0, 2); BARO();
    // ---- ph2
    ldA(0, MQ); STAGE(t2, 2);
    BARO(); LGKM0(); PRIO_MM(MQ, 2); BARO();
    // ---- ph3
    if constexpr (GATES) STAGE(t2, 3); else STAGE(t2, 0);
    BARO(); PRIO_MM(MQ, 0);
    if (j == NITER - 1) { VMW(0); } else { VMW(4); }   // tile 2j+1 landed
    BARO();
    // ---- ph4: tile 2j+1 / dbuf1
    ldA(DB1, 0); ldB(DB1, 0);
    if constexpr (GATES) STAGE(t2, 0); else STAGE(t2, 1);
    BARO(); LGKM0(); PRIO_MM(0, 0); BARO();
    // ---- ph5
    ldB(DB1, 2);
    if constexpr (GATES) STAGE(t2, 1);
    BARO(); LGKM0(); PRIO_MM(0, 2); BARO();
    // ---- ph6
    ldA(DB1, MQ); STAGE(t3, 2);
    BARO(); LGKM0(); PRIO_MM(MQ, 2); BARO();
    // ---- ph7
    if constexpr (GATES) STAGE(t3, 3);
    BARO(); PRIO_MM(MQ, 0);
    if (j == NITER - 1) { VMW(0); }
    else { if constexpr (GATES) VMW(4); else VMW(2); } // tile 2j+2 landed
    BARO();
  }

  // ---- epilogue.  C/D: col=rsel within frag, row=kg*4+q.
  const int row0 = bm * 256 + wm * (GATES ? 128 : 64) + kg * 4;
  const int col0 = bn * BN + wn * 64 + rsel;
  if constexpr (GATES) {
    if (bn < 2) {  // z half (global cols 0..511), block-uniform
#pragma unroll
      for (int mf = 0; mf < 8; ++mf)
#pragma unroll
        for (int nf = 0; nf < 4; ++nf)
#pragma unroll
          for (int q = 0; q < 4; ++q) {
            const int row = row0 + mf * 16 + q;
            const int col = col0 + nf * 16;
            const float zf = 1.f / (1.f + __expf(-acc[mf][nf][q]));
            o_z[(size_t)row * 512 + col] = f2b(zf);
          }
    } else {       // r half (global cols 512..1023)
#pragma unroll
      for (int mf = 0; mf < 8; ++mf)
#pragma unroll
        for (int nf = 0; nf < 4; ++nf)
#pragma unroll
          for (int q = 0; q < 4; ++q) {
            const int row = row0 + mf * 16 + q;
            const int col = col0 + nf * 16 - 512;
            const size_t idx = (size_t)row * 512 + col;
            const float rf = 1.f / (1.f + __expf(-acc[mf][nf][q]));
            o_rh[idx] = f2b(rf * hprev[idx]);
          }
    }
  } else {
#pragma unroll
    for (int mf = 0; mf < 4; ++mf)
#pragma unroll
      for (int nf = 0; nf < 4; ++nf)
#pragma unroll
        for (int q = 0; q < 4; ++q) {
          const int row = row0 + mf * 16 + q;
          const int col = col0 + nf * 16;
          const size_t idx = (size_t)row * 512 + col;
          const float s = acc[mf][nf][q];
          const float hh = 2.f / (1.f + __expf(-2.f * s)) - 1.f;  // tanh
          const float z = b2f(zb_in[idx]);
          o_f[idx] = z * hprev[idx] + (1.f - z) * hh;
        }
  }
}

// ---------------- launch ----------------
extern "C" void kernel_launch(void* const* d_in, const int* in_sizes, int n_in,
                              void* d_out, int out_size, void* d_ws, size_t ws_size,
                              hipStream_t stream) {
  const float* inputs = (const float*)d_in[0];
  const float* h_prev = (const float*)d_in[1];
  const float* Wz = (const float*)d_in[2];
  const float* Wr = (const float*)d_in[3];
  const float* Wh = (const float*)d_in[4];
  float* out = (float*)d_out;

  const int B = 16384, D = 512, U = 512, K = 1024;

  u16* xb = (u16*)d_ws;                 // [B,D] bf16
  u16* hb = xb + (size_t)B * D;         // [B,U] bf16
  u16* wzt = hb + (size_t)B * U;        // [1024,1024]: rows 0-511 Wz^T, 512-1023 Wr^T
  u16* wrt = wzt + (size_t)K * U;
  u16* wht = wrt + (size_t)K * U;       // [512,1024] Wh^T
  u16* zb = wht + (size_t)K * U;        // [B,U] bf16
  u16* rhb = zb + (size_t)B * U;        // [B,U] bf16

  const int n4 = (B * D) / 4;
  cvt_bf16_kernel<<<(n4 + 255) / 256, 256, 0, stream>>>(inputs, xb, n4);
  cvt_bf16_kernel<<<(n4 + 255) / 256, 256, 0, stream>>>(h_prev, hb, n4);
  dim3 tg((K * U + 255) / 256, 3);
  cvt_transpose_kernel<<<tg, 256, 0, stream>>>(Wz, Wr, Wh, wzt, wrt, wht, K, U);

  // gates: N=1024 (z|r), BN=256 -> grid 64*4 = 256 blocks, full chip
  gemm8_kernel<1><<<dim3(256), 512, 0, stream>>>(xb, hb, wzt, h_prev, nullptr, zb, rhb, nullptr);
  // candidate: N=512, BN=128 -> grid 64*4 = 256 blocks, full chip
  gemm8_kernel<0><<<dim3(256), 512, 0, stream>>>(xb, rhb, wht, h_prev, zb, nullptr, nullptr, out);
}